// Round 1
// baseline (252.150 us; speedup 1.0000x reference)
//
#include <hip/hip_runtime.h>
#include <math.h>

#define NQ 12
#define DIM 4096            // 2^12 amplitudes
#define NSAMP 2048          // 64*32 samples
#define NLAYERS 4

struct CnotMasks { unsigned short m[NLAYERS][NQ]; };

// The 12 sequential CNOTs of layer l form a GF(2)-linear index map.
// source(b) = T_0(T_1(...T_11(b))) where T_k flips bit (11-t) if bit (11-c) set,
// c=k, t=(k+r)%12, r = l%11+1.  Decompose into per-bit XOR masks (host-side).
static CnotMasks host_masks() {
    CnotMasks M{};
    for (int l = 0; l < NLAYERS; ++l) {
        int r = l % (NQ - 1) + 1;
        for (int j = 0; j < NQ; ++j) {
            unsigned v = 1u << j;
            for (int k = NQ - 1; k >= 0; --k) {
                int c = k, t = (k + r) % NQ;
                int pc = NQ - 1 - c, pt = NQ - 1 - t;
                if ((v >> pc) & 1u) v ^= (1u << pt);
            }
            M.m[l][j] = (unsigned short)v;
        }
    }
    return M;
}

// ---------------- Kernel A: h = x_perm @ W_in^T + b_in + 1e-6 ----------------
// x: (64,128,32) f32; row s=b*32+m of h uses x[b, :, m].  W_in: (4096,128).
// h: (2048, 4096) f32 in workspace.
__global__ __launch_bounds__(256) void gemm_in_kernel(
        const float* __restrict__ x, const float* __restrict__ Win,
        const float* __restrict__ bin, float* __restrict__ h) {
    __shared__ float xs[64 * 64];   // [l][s], stride 64
    __shared__ float ws[64 * 68];   // [k][l], stride 68 (16B-aligned pad)
    const int tid = threadIdx.x;
    const int kBase = blockIdx.x * 64;
    const int sBase = blockIdx.y * 64;
    const int tx = tid & 15, ty = tid >> 4;
    float acc[4][4];
#pragma unroll
    for (int i = 0; i < 4; ++i)
#pragma unroll
        for (int j = 0; j < 4; ++j) acc[i][j] = 0.f;

    for (int kt = 0; kt < 2; ++kt) {   // K=128 in two 64-chunks
        __syncthreads();
#pragma unroll
        for (int it = 0; it < 16; ++it) {
            int idx = it * 256 + tid;
            int l = idx >> 6, s = idx & 63;
            int sample = sBase + s;
            xs[l * 64 + s] =
                x[(sample >> 5) * 4096 + (kt * 64 + l) * 32 + (sample & 31)];
        }
#pragma unroll
        for (int it = 0; it < 16; ++it) {
            int idx = it * 256 + tid;
            int k = idx >> 6, l = idx & 63;
            ws[k * 68 + l] = Win[(kBase + k) * 128 + kt * 64 + l];
        }
        __syncthreads();
        for (int l0 = 0; l0 < 64; l0 += 4) {
            float xv[4][4], wv[4][4];
#pragma unroll
            for (int d = 0; d < 4; ++d)
                *(float4*)&xv[d][0] = *(const float4*)&xs[(l0 + d) * 64 + tx * 4];
#pragma unroll
            for (int j = 0; j < 4; ++j)
                *(float4*)&wv[j][0] = *(const float4*)&ws[(ty * 4 + j) * 68 + l0];
#pragma unroll
            for (int i = 0; i < 4; ++i)
#pragma unroll
                for (int j = 0; j < 4; ++j)
#pragma unroll
                    for (int d = 0; d < 4; ++d)
                        acc[i][j] += xv[d][i] * wv[j][d];
        }
    }
#pragma unroll
    for (int i = 0; i < 4; ++i) {
        float o[4];
#pragma unroll
        for (int j = 0; j < 4; ++j)
            o[j] = acc[i][j] + bin[kBase + ty * 4 + j] + 1e-6f;
        *(float4*)&h[(size_t)(sBase + tx * 4 + i) * DIM + kBase + ty * 4] =
            *(float4*)&o[0];
    }
}

// ---------------- Kernel B: normalize, simulate circuit, Z expvals, out GEMM --
__global__ __launch_bounds__(256) void qsim_kernel(
        const float* __restrict__ h, const float* __restrict__ qw,
        const float* __restrict__ Wout, const float* __restrict__ bout,
        float* __restrict__ out, CnotMasks M) {
    __shared__ float2 st[DIM];        // 32 KB state
    __shared__ float Ug[NLAYERS * NQ][8];
    __shared__ float red[4];
    __shared__ float wred[4][NQ];
    __shared__ float zsh[NQ];

    const int tid = threadIdx.x;
    const int samp = blockIdx.x;
    const int lane = tid & 63, wv = tid >> 6;

    // ---- Rot gate matrices (once per block; PennyLane Rot = RZ(om)RY(th)RZ(phi))
    if (tid < NLAYERS * NQ) {
        float phi = qw[tid * 3 + 0];
        float th  = qw[tid * 3 + 1];
        float om  = qw[tid * 3 + 2];
        float s, c, sa, ca, sb, cb;
        sincosf(0.5f * th, &s, &c);
        sincosf(0.5f * (phi + om), &sa, &ca);
        sincosf(0.5f * (phi - om), &sb, &cb);
        Ug[tid][0] =  c * ca;  Ug[tid][1] = -c * sa;   // U00 = e^{-ia} c
        Ug[tid][2] = -s * cb;  Ug[tid][3] = -s * sb;   // U01 = -e^{ib} s
        Ug[tid][4] =  s * cb;  Ug[tid][5] = -s * sb;   // U10 = e^{-ib} s
        Ug[tid][6] =  c * ca;  Ug[tid][7] =  c * sa;   // U11 = e^{ia} c
    }

    // ---- load h row, compute norm, write normalized real state
    float vloc[16];
    float ss = 0.f;
#pragma unroll
    for (int j = 0; j < 16; ++j) {
        int a = j * 256 + tid;
        float v = h[(size_t)samp * DIM + a];
        vloc[j] = v;
        ss += v * v;
    }
    for (int o = 32; o > 0; o >>= 1) ss += __shfl_down(ss, o);
    if (lane == 0) red[wv] = ss;
    __syncthreads();
    float inv = 1.0f / sqrtf(red[0] + red[1] + red[2] + red[3]);
#pragma unroll
    for (int j = 0; j < 16; ++j) {
        int a = j * 256 + tid;
        st[a] = make_float2(vloc[j] * inv, 0.f);
    }
    __syncthreads();

    // ---- 4 layers: 12 Rot gates then the CNOT-ring permutation
    for (int l = 0; l < NLAYERS; ++l) {
        for (int w = 0; w < NQ; ++w) {
            const int p = NQ - 1 - w;                 // flat bit of wire w
            const float* U = Ug[l * NQ + w];
            const float u00r = U[0], u00i = U[1], u01r = U[2], u01i = U[3];
            const float u10r = U[4], u10i = U[5], u11r = U[6], u11i = U[7];
            const unsigned lowmask = (1u << p) - 1u;
#pragma unroll
            for (int j = 0; j < 8; ++j) {
                unsigned q = j * 256 + tid;           // pair index 0..2047
                unsigned i0 = ((q & ~lowmask) << 1) | (q & lowmask);
                unsigned i1 = i0 | (1u << p);
                float2 a0 = st[i0], a1 = st[i1];
                float n0r = u00r * a0.x - u00i * a0.y + u01r * a1.x - u01i * a1.y;
                float n0i = u00r * a0.y + u00i * a0.x + u01r * a1.y + u01i * a1.x;
                float n1r = u10r * a0.x - u10i * a0.y + u11r * a1.x - u11i * a1.y;
                float n1i = u10r * a0.y + u10i * a0.x + u11r * a1.y + u11i * a1.x;
                st[i0] = make_float2(n0r, n0i);
                st[i1] = make_float2(n1r, n1i);
            }
            __syncthreads();
        }
        // fused CNOT-ring permutation: new[b] = old[src(b)], src GF(2)-linear
        unsigned srcT = 0;
#pragma unroll
        for (int b = 0; b < 8; ++b)
            if ((tid >> b) & 1) srcT ^= M.m[l][b];
        float2 tmp[16];
#pragma unroll
        for (int j = 0; j < 16; ++j) {
            unsigned srcH = 0;
#pragma unroll
            for (int b = 0; b < 4; ++b)
                if ((j >> b) & 1) srcH ^= M.m[l][8 + b];
            tmp[j] = st[srcT ^ srcH];
        }
        __syncthreads();
#pragma unroll
        for (int j = 0; j < 16; ++j) st[j * 256 + tid] = tmp[j];
        __syncthreads();
    }

    // ---- PauliZ expvals: z_i = sum_b (+/-)|amp|^2, sign = bit (11-i)
    float zp[NQ];
#pragma unroll
    for (int i = 0; i < NQ; ++i) zp[i] = 0.f;
#pragma unroll
    for (int j = 0; j < 16; ++j) {
        int a = j * 256 + tid;
        float2 v = st[a];
        float pr = v.x * v.x + v.y * v.y;
#pragma unroll
        for (int i = 0; i < NQ; ++i)
            zp[i] += ((a >> (NQ - 1 - i)) & 1) ? -pr : pr;
    }
#pragma unroll
    for (int i = 0; i < NQ; ++i) {
        float v = zp[i];
        for (int o = 32; o > 0; o >>= 1) v += __shfl_down(v, o);
        if (lane == 0) wred[wv][i] = v;
    }
    __syncthreads();
    if (tid < NQ)
        zsh[tid] = wred[0][tid] + wred[1][tid] + wred[2][tid] + wred[3][tid];
    __syncthreads();

    // ---- out[b, f, m] = b_out[f] + sum_i z_i * W_out[f,i]
    if (tid < 96) {
        float acc = bout[tid];
#pragma unroll
        for (int i = 0; i < NQ; ++i) acc += zsh[i] * Wout[tid * NQ + i];
        int b = samp >> 5, m = samp & 31;
        out[b * (96 * 32) + tid * 32 + m] = acc;
    }
}

extern "C" void kernel_launch(void* const* d_in, const int* in_sizes, int n_in,
                              void* d_out, int out_size, void* d_ws, size_t ws_size,
                              hipStream_t stream) {
    const float* x    = (const float*)d_in[0];
    const float* Win  = (const float*)d_in[1];
    const float* bin  = (const float*)d_in[2];
    const float* qw   = (const float*)d_in[3];
    const float* Wout = (const float*)d_in[4];
    const float* bout = (const float*)d_in[5];
    float* h = (float*)d_ws;   // 2048*4096*4 = 32 MB scratch

    CnotMasks M = host_masks();

    gemm_in_kernel<<<dim3(64, 32), 256, 0, stream>>>(x, Win, bin, h);
    qsim_kernel<<<dim3(NSAMP), 256, 0, stream>>>(h, qw, Wout, bout,
                                                 (float*)d_out, M);
}

// Round 3
// 217.793 us; speedup vs baseline: 1.1577x; 1.1577x over previous
//
#include <hip/hip_runtime.h>
#include <math.h>

#define NQ 12
#define DIM 4096            // 2^12 amplitudes
#define NSAMP 2048          // 64*32 samples
#define NLAYERS 4

struct CnotMasks { unsigned short m[NLAYERS][NQ]; };

// The 12 sequential CNOTs of layer l form a GF(2)-linear index map.
// src(b) = XOR over set bits j of b of m[l][j]  (verified in round 1).
static CnotMasks host_masks() {
    CnotMasks M{};
    for (int l = 0; l < NLAYERS; ++l) {
        int r = l % (NQ - 1) + 1;
        for (int j = 0; j < NQ; ++j) {
            unsigned v = 1u << j;
            for (int k = NQ - 1; k >= 0; --k) {
                int c = k, t = (k + r) % NQ;
                int pc = NQ - 1 - c, pt = NQ - 1 - t;
                if ((v >> pc) & 1u) v ^= (1u << pt);
            }
            M.m[l][j] = (unsigned short)v;
        }
    }
    return M;
}

// ---------------- Kernel A: h = x_perm @ W_in^T + b_in + 1e-6 ----------------
__global__ __launch_bounds__(256) void gemm_in_kernel(
        const float* __restrict__ x, const float* __restrict__ Win,
        const float* __restrict__ bin, float* __restrict__ h) {
    __shared__ float xs[64 * 64];   // [l][s]
    __shared__ float ws[64 * 68];   // [k][l], padded
    const int tid = threadIdx.x;
    const int kBase = blockIdx.x * 64;
    const int sBase = blockIdx.y * 64;
    const int tx = tid & 15, ty = tid >> 4;
    float acc[4][4];
#pragma unroll
    for (int i = 0; i < 4; ++i)
#pragma unroll
        for (int j = 0; j < 4; ++j) acc[i][j] = 0.f;

    for (int kt = 0; kt < 2; ++kt) {
        __syncthreads();
#pragma unroll
        for (int it = 0; it < 16; ++it) {
            int idx = it * 256 + tid;
            int l = idx >> 6, s = idx & 63;
            int sample = sBase + s;
            xs[l * 64 + s] =
                x[(sample >> 5) * 4096 + (kt * 64 + l) * 32 + (sample & 31)];
        }
#pragma unroll
        for (int it = 0; it < 16; ++it) {
            int idx = it * 256 + tid;
            int k = idx >> 6, l = idx & 63;
            ws[k * 68 + l] = Win[(kBase + k) * 128 + kt * 64 + l];
        }
        __syncthreads();
        for (int l0 = 0; l0 < 64; l0 += 4) {
            float xv[4][4], wv[4][4];
#pragma unroll
            for (int d = 0; d < 4; ++d)
                *(float4*)&xv[d][0] = *(const float4*)&xs[(l0 + d) * 64 + tx * 4];
#pragma unroll
            for (int j = 0; j < 4; ++j)
                *(float4*)&wv[j][0] = *(const float4*)&ws[(ty * 4 + j) * 68 + l0];
#pragma unroll
            for (int i = 0; i < 4; ++i)
#pragma unroll
                for (int j = 0; j < 4; ++j)
#pragma unroll
                    for (int d = 0; d < 4; ++d)
                        acc[i][j] += xv[d][i] * wv[j][d];
        }
    }
#pragma unroll
    for (int i = 0; i < 4; ++i) {
        float o[4];
#pragma unroll
        for (int j = 0; j < 4; ++j)
            o[j] = acc[i][j] + bin[kBase + ty * 4 + j] + 1e-6f;
        *(float4*)&h[(size_t)(sBase + tx * 4 + i) * DIM + kBase + ty * 4] =
            *(float4*)&o[0];
    }
}

// ---------------- Kernel B: register-resident state-vector simulator ---------
// Amp index a = (j<<8) | tid :  j = bits 8-11 (register), tid bits 6-7 = wave,
// tid bits 0-5 = lane.  Per layer: reg gates (wires 0-3), shfl gates (wires
// 6-11), then ONE fused LDS pass = 2-qubit wave gate (wires 4,5) + CNOT perm.
__global__ __launch_bounds__(256, 4) void qsim_kernel(
        const float* __restrict__ h, const float* __restrict__ qw,
        const float* __restrict__ Wout, const float* __restrict__ bout,
        float* __restrict__ out, CnotMasks M) {
    __shared__ float2 st[DIM];              // 32 KB staging for fused pass
    __shared__ float Ug[NLAYERS * NQ][8];   // gate matrices
    __shared__ float2 u4s[16];              // fused wave-gate 4x4 (per layer)
    __shared__ float red[4];
    __shared__ float wred[4][NQ];
    __shared__ float zsh[NQ];

    const int tid = threadIdx.x;
    const int samp = blockIdx.x;
    const int lane = tid & 63, wv = tid >> 6;

    // ---- Rot matrices (PennyLane Rot = RZ(om)RY(th)RZ(phi))
    if (tid < NLAYERS * NQ) {
        float phi = qw[tid * 3 + 0];
        float th  = qw[tid * 3 + 1];
        float om  = qw[tid * 3 + 2];
        float s, c, sa, ca, sb, cb;
        sincosf(0.5f * th, &s, &c);
        sincosf(0.5f * (phi + om), &sa, &ca);
        sincosf(0.5f * (phi - om), &sb, &cb);
        Ug[tid][0] =  c * ca;  Ug[tid][1] = -c * sa;   // u00
        Ug[tid][2] = -s * cb;  Ug[tid][3] = -s * sb;   // u01
        Ug[tid][4] =  s * cb;  Ug[tid][5] = -s * sb;   // u10
        Ug[tid][6] =  c * ca;  Ug[tid][7] =  c * sa;   // u11
    }

    // ---- load h row (coalesced), norm
    float vloc[16];
    float ss = 0.f;
#pragma unroll
    for (int j = 0; j < 16; ++j) {
        float v = h[(size_t)samp * DIM + (j << 8) + tid];
        vloc[j] = v;
        ss += v * v;
    }
#pragma unroll
    for (int o = 32; o > 0; o >>= 1) ss += __shfl_xor(ss, o);
    if (lane == 0) red[wv] = ss;
    __syncthreads();     // also covers Ug init
    const float inv = 1.0f / sqrtf(red[0] + red[1] + red[2] + red[3]);
    float2 v[16];
#pragma unroll
    for (int j = 0; j < 16; ++j) v[j] = make_float2(vloc[j] * inv, 0.f);

    // ---- layers
    for (int l = 0; l < NLAYERS; ++l) {
        const int gbase = l * NQ;

        // register gates: wires 0..3 act on bit (8+q) of a, q = 3-w
#pragma unroll
        for (int q = 0; q < 4; ++q) {
            const float* U = Ug[gbase + 3 - q];
            const float u00r = U[0], u00i = U[1], u01r = U[2], u01i = U[3];
            const float u10r = U[4], u10i = U[5], u11r = U[6], u11i = U[7];
#pragma unroll
            for (int j = 0; j < 16; ++j) {
                if (!((j >> q) & 1)) {
                    const int j1 = j | (1 << q);
                    float2 a0 = v[j], a1 = v[j1];
                    v[j].x  = u00r * a0.x - u00i * a0.y + u01r * a1.x - u01i * a1.y;
                    v[j].y  = u00r * a0.y + u00i * a0.x + u01r * a1.y + u01i * a1.x;
                    v[j1].x = u10r * a0.x - u10i * a0.y + u11r * a1.x - u11i * a1.y;
                    v[j1].y = u10r * a0.y + u10i * a0.x + u11r * a1.y + u11i * a1.x;
                }
            }
        }

        // shuffle gates: wires 6..11 act on lane bit p = 11-w
#pragma unroll
        for (int p = 0; p < 6; ++p) {
            const float* U = Ug[gbase + 11 - p];
            const int bit = (tid >> p) & 1;
            const float cAr = bit ? U[6] : U[0];
            const float cAi = bit ? U[7] : U[1];
            const float cBr = bit ? U[4] : U[2];
            const float cBi = bit ? U[5] : U[3];
#pragma unroll
            for (int j = 0; j < 16; ++j) {
                float px = __shfl_xor(v[j].x, 1 << p);
                float py = __shfl_xor(v[j].y, 1 << p);
                float nx = cAr * v[j].x - cAi * v[j].y + cBr * px - cBi * py;
                float ny = cAr * v[j].y + cAi * v[j].x + cBr * py + cBi * px;
                v[j] = make_float2(nx, ny);
            }
        }

        // 4x4 wave-gate matrix (wires 4,5 on bits 7,6): U4[h][k] = U4[h1k1]*U5[h0k0]
        if (tid < 16) {
            const int hh = tid >> 2, kk = tid & 3;
            const float* A = Ug[gbase + 4];
            const float* B = Ug[gbase + 5];
            const int ai = ((hh >> 1) * 2 + (kk >> 1)) * 2;
            const int bi = ((hh & 1) * 2 + (kk & 1)) * 2;
            float ar = A[ai], aim = A[ai + 1], br = B[bi], bim = B[bi + 1];
            u4s[tid] = make_float2(ar * br - aim * bim, ar * bim + aim * br);
        }

        // stage state
#pragma unroll
        for (int j = 0; j < 16; ++j) st[(j << 8) | tid] = v[j];
        __syncthreads();

        // fused: out[b] = sum_k U4[(Lb>>6)&3][k] * y[(Lb & ~0xC0)|(k<<6)]
        unsigned sA = 0;
#pragma unroll
        for (int b = 0; b < 8; ++b)
            if ((tid >> b) & 1) sA ^= M.m[l][b];
        const unsigned c8 = M.m[l][8], c9 = M.m[l][9];
        const unsigned c10 = M.m[l][10], c11 = M.m[l][11];
#pragma unroll
        for (int j = 0; j < 16; ++j) {
            unsigned s = sA;
            if (j & 1) s ^= c8;
            if (j & 2) s ^= c9;
            if (j & 4) s ^= c10;
            if (j & 8) s ^= c11;
            const unsigned sl = s & ~0xC0u;
            const unsigned row = (s >> 6) & 3u;
            float2 g0 = st[sl];
            float2 g1 = st[sl | 0x40u];
            float2 g2 = st[sl | 0x80u];
            float2 g3 = st[sl | 0xC0u];
            float4 rA = *(const float4*)&u4s[row * 4];      // c0,c1
            float4 rB = *(const float4*)&u4s[row * 4 + 2];  // c2,c3
            float nx = rA.x * g0.x - rA.y * g0.y + rA.z * g1.x - rA.w * g1.y
                     + rB.x * g2.x - rB.y * g2.y + rB.z * g3.x - rB.w * g3.y;
            float ny = rA.x * g0.y + rA.y * g0.x + rA.z * g1.y + rA.w * g1.x
                     + rB.x * g2.y + rB.y * g2.x + rB.z * g3.y + rB.w * g3.x;
            v[j] = make_float2(nx, ny);
        }
        __syncthreads();   // WAR guard before next layer's staging writes
    }

    // ---- PauliZ expvals: sign_i = bit (11-i) of a;  a = (j<<8)|tid
    float fs[12];
#pragma unroll
    for (int i = 0; i < 12; ++i)
        fs[i] = (i < 4) ? 1.f : (((tid >> (11 - i)) & 1) ? -1.f : 1.f);
    float zp[12];
#pragma unroll
    for (int i = 0; i < 12; ++i) zp[i] = 0.f;
#pragma unroll
    for (int j = 0; j < 16; ++j) {
        float2 a = v[j];
        float pr = a.x * a.x + a.y * a.y;
#pragma unroll
        for (int i = 0; i < 12; ++i) {
            const bool neg = (i < 4) && ((j >> (3 - i)) & 1);
            zp[i] = fmaf(pr, neg ? -fs[i] : fs[i], zp[i]);
        }
    }
#pragma unroll
    for (int i = 0; i < 12; ++i) {
        float z = zp[i];
#pragma unroll
        for (int o = 32; o > 0; o >>= 1) z += __shfl_xor(z, o);
        if (lane == 0) wred[wv][i] = z;
    }
    __syncthreads();
    if (tid < NQ)
        zsh[tid] = wred[0][tid] + wred[1][tid] + wred[2][tid] + wred[3][tid];
    __syncthreads();

    if (tid < 96) {
        float acc = bout[tid];
#pragma unroll
        for (int i = 0; i < NQ; ++i) acc += zsh[i] * Wout[tid * NQ + i];
        int b = samp >> 5, m = samp & 31;
        out[b * (96 * 32) + tid * 32 + m] = acc;
    }
}

extern "C" void kernel_launch(void* const* d_in, const int* in_sizes, int n_in,
                              void* d_out, int out_size, void* d_ws, size_t ws_size,
                              hipStream_t stream) {
    const float* x    = (const float*)d_in[0];
    const float* Win  = (const float*)d_in[1];
    const float* bin  = (const float*)d_in[2];
    const float* qw   = (const float*)d_in[3];
    const float* Wout = (const float*)d_in[4];
    const float* bout = (const float*)d_in[5];
    float* h = (float*)d_ws;   // 32 MB scratch

    CnotMasks M = host_masks();

    gemm_in_kernel<<<dim3(64, 32), 256, 0, stream>>>(x, Win, bin, h);
    qsim_kernel<<<dim3(NSAMP), 256, 0, stream>>>(h, qw, Wout, bout,
                                                 (float*)d_out, M);
}